// Round 12
// baseline (120.768 us; speedup 1.0000x reference)
//
#include <hip/hip_runtime.h>
#include <hip/hip_bf16.h>

// Problem constants (reference: N=768, D_IN=308, H=100, iterations=1)
// Inputs f32, output f32 (verified round 4). hh==0 on the single iteration,
// so B_W[500:600], B2_Wh, D_W/b are dead.
#define NW   768
#define HID  100
#define DIN  308
#define RPB  2          // rows per block, stages A/B (384 blocks)
#define NBLK 432        // 12 x 12 x 3 pair tiles of 64x64
#define NTHR 512
#define LDP  108        // stage-C row stride (mod4==0 -> aligned b128)

typedef const float* fp;

// ---------------------------------------------------------------------------
// Device-scope spin barrier. Counters zeroed by an in-graph hipMemsetAsync
// before each kernel run. Co-residency: LDS 56.1KB -> 2 blocks/CU -> capacity
// 512 >= 432 launched blocks, nothing else on the GPU.
// ---------------------------------------------------------------------------
__device__ __forceinline__ void gbar(int* bar, int idx) {
    __syncthreads();
    if (threadIdx.x == 0) {
        __hip_atomic_fetch_add(&bar[idx], 1, __ATOMIC_RELEASE,
                               __HIP_MEMORY_SCOPE_AGENT);
        while (__hip_atomic_load(&bar[idx], __ATOMIC_RELAXED,
                                 __HIP_MEMORY_SCOPE_AGENT) < NBLK) {
            __builtin_amdgcn_s_sleep(8);
        }
        (void)__hip_atomic_load(&bar[idx], __ATOMIC_ACQUIRE,
                                __HIP_MEMORY_SCOPE_AGENT);
    }
    __syncthreads();
}

// ---------------------------------------------------------------------------
// Single kernel: stage A (uu) -> bar -> stage B (gather/bb/oo/hl/hr) -> bar
// -> stage C (64x64 pairwise tiles). LDS union = 14032 floats (56.1 KB).
// ---------------------------------------------------------------------------
__global__ __launch_bounds__(NTHR, 4) void k_all(
    fp vv, const int* __restrict__ indices, const int* __restrict__ nf,
    fp A_W, fp A_b, fp B_W, fp B_b, fp B2_Wo, fp B2_bo,
    fp W1r, fp b1r, fp W1c, fp b1c, fp W1e, fp b1e,
    fp W2r, fp b2r, fp W2c, fp b2c, fp W2e, fp b2e,
    float* __restrict__ uu, float* __restrict__ hlhr, int* __restrict__ bar,
    float* __restrict__ out) {
    __shared__ __align__(16) float smem[14032];
    const int bid = blockIdx.x;
    const int tid = threadIdx.x;

    // ======================= Stage A: uu = tanh(vv@A_W + A_b) ==============
    if (bid < NW / RPB) {
        float (*vs)[DIN]        = (float(*)[DIN])smem;              // [2][308]
        float (*part)[RPB][128] = (float(*)[RPB][128])(smem + 616); // [4][2][128]
        const int i0 = bid * RPB;
        for (int t = tid; t < RPB * DIN; t += NTHR) {
            const int r = t / DIN, k = t % DIN;
            vs[r][k] = vv[(i0 + r) * DIN + k];
        }
        __syncthreads();
        const int c = tid & 127;
        const int s = tid >> 7;          // 0..3, k-slice of 77
        float a0 = 0.f, a1 = 0.f;
        if (c < HID) {
            const int k0 = s * 77;
#pragma unroll 11
            for (int k = k0; k < k0 + 77; ++k) {
                const float w = A_W[k * HID + c];
                a0 = fmaf(vs[0][k], w, a0);
                a1 = fmaf(vs[1][k], w, a1);
            }
        }
        part[s][0][c] = a0; part[s][1][c] = a1;
        __syncthreads();
        for (int t = tid; t < RPB * HID; t += NTHR) {
            const int r = t / HID, cc = t % HID;
            float acc = A_b[cc];
#pragma unroll
            for (int s2 = 0; s2 < 4; ++s2) acc += part[s2][r][cc];
            uu[(i0 + r) * HID + cc] = tanhf(acc);
        }
    }
    gbar(bar, 0);

    // ======================= Stage B: fused gather->bb->oo->hl/hr ==========
    if (bid < NW / RPB) {
        float (*ww)[500]        = (float(*)[500])smem;               // [2][500]
        float (*part)[RPB][128] = (float(*)[RPB][128])(smem + 1000); // [4][2][128]
        float (*bbs)[HID]       = (float(*)[HID])(smem + 2024);      // [2][100]
        float (*oos)[HID]       = (float(*)[HID])(smem + 2224);      // [2][100]
        int*  flags             = (int*)(smem + 14024);              // [8]

        if (tid < 8) flags[tid] = 0;
        __syncthreads();
        if (tid < 192) {
            const int t = tid;
            const unsigned vn = (unsigned)nf[t];
            if (vn > 1u) atomicOr(&flags[0], 1);
            if (vn & 0xFEFEFEFEu) atomicOr(&flags[1], 1);
            if ((t & 1) && vn) atomicOr(&flags[2], 1);
            if (!(t & 1) && vn) atomicOr(&flags[3], 1);
            const unsigned vi = (unsigned)indices[t];
            if ((t & 1) && vi) atomicOr(&flags[4], 1);
            if (!(t & 1) && vi) atomicOr(&flags[5], 1);
        }
        __syncthreads();
        if (tid == 0) {
            int m = 0;
            if (!flags[1] && flags[0]) m = 1;            // packed uint8 bools
            else if (!flags[2] && flags[3]) m = 2;       // int64 per element
            flags[6] = m;
            flags[7] = (!flags[4] && flags[5]) ? 1 : 0;  // idx int64?
        }
        __syncthreads();
        const int mnf = flags[6], midx = flags[7];

        const int i0 = bid * RPB;
        for (int t = tid; t < RPB * 5 * HID; t += NTHR) {
            const int r = t / (5 * HID), u = t % (5 * HID);
            const int i = i0 + r;
            const bool notf = (mnf == 1) ? (((const unsigned char*)nf)[i] != 0)
                            : (mnf == 2) ? (nf[2 * i] != 0)
                                         : (nf[i] != 0);
            const int q = u / HID, cc = u % HID;
            int j = midx ? indices[2 * (i * 5 + q)] : indices[i * 5 + q];
            j = (j < 0) ? 0 : ((j >= NW) ? NW - 1 : j);
            ww[r][u] = notf ? 0.f : uu[j * HID + cc];
        }
        __syncthreads();

        const int c = tid & 127;
        const int s = tid >> 7;        // 0..3

        {   // B-stage: K=500 in 4 slices {128,128,128,116}, 16B-aligned
            float a0 = 0.f, a1 = 0.f;
            if (c < HID) {
                const int k0 = s * 128;
                const int k1 = (s < 3) ? k0 + 128 : 500;
                for (int k = k0; k < k1; k += 4) {
                    const float4 w0 = *(const float4*)&ww[0][k];
                    const float4 w1 = *(const float4*)&ww[1][k];
                    const float b0 = B_W[(k + 0) * HID + c];
                    const float b1v = B_W[(k + 1) * HID + c];
                    const float b2v = B_W[(k + 2) * HID + c];
                    const float b3 = B_W[(k + 3) * HID + c];
                    a0 = fmaf(w0.x, b0, a0); a1 = fmaf(w1.x, b0, a1);
                    a0 = fmaf(w0.y, b1v, a0); a1 = fmaf(w1.y, b1v, a1);
                    a0 = fmaf(w0.z, b2v, a0); a1 = fmaf(w1.z, b2v, a1);
                    a0 = fmaf(w0.w, b3, a0); a1 = fmaf(w1.w, b3, a1);
                }
            }
            part[s][0][c] = a0; part[s][1][c] = a1;
        }
        __syncthreads();
        for (int t = tid; t < RPB * HID; t += NTHR) {
            const int r = t / HID, cc = t % HID;
            float acc = B_b[cc];
#pragma unroll
            for (int s2 = 0; s2 < 4; ++s2) acc += part[s2][r][cc];
            bbs[r][cc] = tanhf(acc);
        }
        __syncthreads();

        {   // oo-stage: K=100 in 4 slices {28,28,28,16}, 16B-aligned
            float a0 = 0.f, a1 = 0.f;
            if (c < HID) {
                const int k0 = s * 28;
                const int k1 = (s < 3) ? k0 + 28 : 100;
                for (int k = k0; k < k1; k += 4) {
                    const float4 w0 = *(const float4*)&bbs[0][k];
                    const float4 w1 = *(const float4*)&bbs[1][k];
                    const float b0 = B2_Wo[(k + 0) * HID + c];
                    const float b1v = B2_Wo[(k + 1) * HID + c];
                    const float b2v = B2_Wo[(k + 2) * HID + c];
                    const float b3 = B2_Wo[(k + 3) * HID + c];
                    a0 = fmaf(w0.x, b0, a0); a1 = fmaf(w1.x, b0, a1);
                    a0 = fmaf(w0.y, b1v, a0); a1 = fmaf(w1.y, b1v, a1);
                    a0 = fmaf(w0.z, b2v, a0); a1 = fmaf(w1.z, b2v, a1);
                    a0 = fmaf(w0.w, b3, a0); a1 = fmaf(w1.w, b3, a1);
                }
            }
            part[s][0][c] = a0; part[s][1][c] = a1;
        }
        __syncthreads();
        for (int t = tid; t < RPB * HID; t += NTHR) {
            const int r = t / HID, cc = t % HID;
            float acc = B2_bo[cc];
#pragma unroll
            for (int s2 = 0; s2 < 4; ++s2) acc += part[s2][r][cc];
            oos[r][cc] = tanhf(acc);
        }
        __syncthreads();

        // W1-stage: 600 outputs (3 heads x hl/hr x 100 cols), K=100
        for (int u = tid; u < 600; u += NTHR) {
            const int ho = u / HID;
            const int cc = u % HID;
            const int h = ho >> 1, half = ho & 1;
            fp W1 = (h == 0) ? W1r : ((h == 1) ? W1c : W1e);
            fp b1 = (h == 0) ? b1r : ((h == 1) ? b1c : b1e);
            const float bias = half ? 0.f : b1[cc];
            float a0 = bias, a1 = bias;
            const float* Wp = W1 + half * HID * HID;
#pragma unroll 5
            for (int k = 0; k < HID; k += 4) {
                const float4 o0 = *(const float4*)&oos[0][k];
                const float4 o1 = *(const float4*)&oos[1][k];
                const float b0 = Wp[(k + 0) * HID + cc];
                const float b1v = Wp[(k + 1) * HID + cc];
                const float b2v = Wp[(k + 2) * HID + cc];
                const float b3 = Wp[(k + 3) * HID + cc];
                a0 = fmaf(o0.x, b0, a0); a1 = fmaf(o1.x, b0, a1);
                a0 = fmaf(o0.y, b1v, a0); a1 = fmaf(o1.y, b1v, a1);
                a0 = fmaf(o0.z, b2v, a0); a1 = fmaf(o1.z, b2v, a1);
                a0 = fmaf(o0.w, b3, a0); a1 = fmaf(o1.w, b3, a1);
            }
            hlhr[(size_t)ho * (NW * HID) + (size_t)(i0 + 0) * HID + cc] = a0;
            hlhr[(size_t)ho * (NW * HID) + (size_t)(i0 + 1) * HID + cc] = a1;
        }
    }
    gbar(bar, 1);

    // ======================= Stage C: 64x64 pairwise tile ==================
    {
        float* hlS = smem;                 // [64][108] flat
        float* hrS = smem + 64 * LDP;      // [64][108] flat
        float* w2a = smem + 2 * 64 * LDP;  // [100]
        float* w2b = w2a + HID;            // [100]

        const int h   = bid / 144;
        const int rem = bid % 144;
        const int i0  = (rem / 12) * 64;
        const int j0  = (rem % 12) * 64;
        const float* hl = hlhr + (size_t)(h * 2 + 0) * (NW * HID) + (size_t)i0 * HID;
        const float* hr = hlhr + (size_t)(h * 2 + 1) * (NW * HID) + (size_t)j0 * HID;
        fp W2 = (h == 0) ? W2r : ((h == 1) ? W2c : W2e);
        fp b2 = (h == 0) ? b2r : ((h == 1) ? b2c : b2e);

        for (int t = tid; t < 64 * HID; t += NTHR) {
            const int r = t / HID, c = t % HID;
            hlS[r * LDP + c] = hl[t];
            hrS[r * LDP + c] = hr[t];
        }
        if (tid < HID) {
            w2a[tid] = W2[2 * tid];
            w2b[tid] = W2[2 * tid + 1];
        }
        __syncthreads();

        const int tx = tid & 15;    // j-groups: tx, tx+16, tx+32, tx+48
        const int ty = tid >> 4;    // 0..31 -> i rows ty*2, ty*2+1
        float acc0[2][4] = {};
        float acc1[2][4] = {};

        for (int kb = 0; kb < HID; kb += 4) {
            const float4 a0 = *(const float4*)&hlS[(ty * 2 + 0) * LDP + kb];
            const float4 a1 = *(const float4*)&hlS[(ty * 2 + 1) * LDP + kb];
            const float4 r0 = *(const float4*)&hrS[(tx +  0) * LDP + kb];
            const float4 r1 = *(const float4*)&hrS[(tx + 16) * LDP + kb];
            const float4 r2 = *(const float4*)&hrS[(tx + 32) * LDP + kb];
            const float4 r3 = *(const float4*)&hrS[(tx + 48) * LDP + kb];
            const float4 wa = *(const float4*)&w2a[kb];
            const float4 wb = *(const float4*)&w2b[kb];
#define STEP(cmp)                                                              \
            {                                                                  \
                const float av0 = a0.cmp, av1 = a1.cmp;                        \
                const float rv[4] = {r0.cmp, r1.cmp, r2.cmp, r3.cmp};          \
                const float wav = wa.cmp, wbv = wb.cmp;                        \
                _Pragma("unroll")                                              \
                for (int g = 0; g < 4; ++g) {                                  \
                    const float h0 = fmaxf(av0 + rv[g], 0.f);                  \
                    const float h1 = fmaxf(av1 + rv[g], 0.f);                  \
                    acc0[0][g] = fmaf(h0, wav, acc0[0][g]);                    \
                    acc1[0][g] = fmaf(h0, wbv, acc1[0][g]);                    \
                    acc0[1][g] = fmaf(h1, wav, acc0[1][g]);                    \
                    acc1[1][g] = fmaf(h1, wbv, acc1[1][g]);                    \
                }                                                              \
            }
            STEP(x) STEP(y) STEP(z) STEP(w)
#undef STEP
        }

        const float b20 = b2[0];
        const float b21 = b2[1];
#pragma unroll
        for (int ii = 0; ii < 2; ++ii) {
            const int i = i0 + ty * 2 + ii;
#pragma unroll
            for (int g = 0; g < 4; ++g) {
                const int j = j0 + tx + 16 * g;
                const size_t o = ((size_t)(h * NW + i) * NW + j) * 2;
                float2 v;
                v.x = acc0[ii][g] + b20;
                v.y = acc1[ii][g] + b21;
                *reinterpret_cast<float2*>(out + o) = v;
            }
        }
    }
}

// ---------------------------------------------------------------------------
extern "C" void kernel_launch(void* const* d_in, const int* in_sizes, int n_in,
                              void* d_out, int out_size, void* d_ws,
                              size_t ws_size, hipStream_t stream) {
    int i_vv = -1, i_idx = -1, i_nf = -1, i_AW = -1, i_BW = -1;
    int tens[3] = {-1, -1, -1}; int n10 = 0;   // B2_Wo, B2_Wh, D_W
    int w1s[3]  = {-1, -1, -1}; int n20 = 0;
    int w2s_[3] = {-1, -1, -1}; int n200 = 0;
    int b100[8] = {-1, -1, -1, -1, -1, -1, -1, -1}; int nb = 0;
    int b2s[3]  = {-1, -1, -1}; int nb2 = 0;
    for (int i = 0; i < n_in; ++i) {
        switch (in_sizes[i]) {
            case 236544: i_vv = i; break;
            case 3840:   i_idx = i; break;
            case 768:    i_nf = i; break;
            case 30800:  i_AW = i; break;
            case 60000:  i_BW = i; break;
            case 10000:  if (n10 < 3) tens[n10++] = i; break;
            case 20000:  if (n20 < 3) w1s[n20++] = i; break;
            case 200:    if (n200 < 3) w2s_[n200++] = i; break;
            case 100:    if (nb < 8) b100[nb++] = i; break;
            case 2:      if (nb2 < 3) b2s[nb2++] = i; break;
            default: break;  // num_words (size 1)
        }
    }
    fp vv          = (fp)d_in[i_vv];
    const int* idx = (const int*)d_in[i_idx];
    const int* nf  = (const int*)d_in[i_nf];
    fp A_W = (fp)d_in[i_AW],      A_b   = (fp)d_in[b100[0]];
    fp B_W = (fp)d_in[i_BW],      B_b   = (fp)d_in[b100[1]];
    fp B2_Wo = (fp)d_in[tens[0]], B2_bo = (fp)d_in[b100[2]];
    fp W1r = (fp)d_in[w1s[0]], b1r = (fp)d_in[b100[5]];
    fp W1c = (fp)d_in[w1s[1]], b1c = (fp)d_in[b100[6]];
    fp W1e = (fp)d_in[w1s[2]], b1e = (fp)d_in[b100[7]];
    fp W2r = (fp)d_in[w2s_[0]], b2r = (fp)d_in[b2s[0]];
    fp W2c = (fp)d_in[w2s_[1]], b2c = (fp)d_in[b2s[1]];
    fp W2e = (fp)d_in[w2s_[2]], b2e = (fp)d_in[b2s[2]];

    float* out  = (float*)d_out;
    float* ws   = (float*)d_ws;
    float* uu   = ws;                            // 76800 f32
    float* hlhr = ws + NW * HID;                 // [6][768][100] f32
    int*   bar  = (int*)(ws + NW * HID + 6 * NW * HID);  // 2 ints

    // zero the barrier counters inside the graph (d_ws is poisoned to 0xAA)
    hipMemsetAsync((void*)bar, 0, 2 * sizeof(int), stream);

    k_all<<<NBLK, NTHR, 0, stream>>>(vv, idx, nf,
                                     A_W, A_b, B_W, B_b, B2_Wo, B2_bo,
                                     W1r, b1r, W1c, b1c, W1e, b1e,
                                     W2r, b2r, W2c, b2c, W2e, b2e,
                                     uu, hlhr, bar, out);
}

// Round 13
// 56.150 us; speedup vs baseline: 2.1508x; 2.1508x over previous
//
#include <hip/hip_runtime.h>
#include <hip/hip_bf16.h>

// Problem constants (reference: N=768, D_IN=308, H=100, iterations=1)
// Inputs f32, output f32 (verified round 4). hh==0 on the single iteration,
// so B_W[500:600], B2_Wh, D_W/b are dead.
#define NW   768
#define HID  100
#define DIN  308
#define RPB  2          // rows per block in k_uu / k_fused
#define TP   32         // pair-tile edge
#define LDP  108        // hl row stride (mod4==0 -> aligned b128)

typedef const float* fp;
typedef float f32x2 __attribute__((ext_vector_type(2)));
typedef float f32x4 __attribute__((ext_vector_type(4)));

// ---------------------------------------------------------------------------
// K1: uu = tanh(vv @ A_W + A_b).  (identical to rounds 7-11)
// ---------------------------------------------------------------------------
__global__ __launch_bounds__(512) void k_uu(fp vv, fp A_W, fp A_b,
                                            float* __restrict__ uu) {
    __shared__ float vs[RPB][DIN];
    __shared__ float part[4][RPB][128];
    const int i0 = blockIdx.x * RPB;
    for (int t = threadIdx.x; t < RPB * DIN; t += 512) {
        const int r = t / DIN, k = t % DIN;
        vs[r][k] = vv[(i0 + r) * DIN + k];
    }
    __syncthreads();
    const int c = threadIdx.x & 127;
    const int s = threadIdx.x >> 7;
    float a0 = 0.f, a1 = 0.f;
    if (c < HID) {
        const int k0 = s * 77;
#pragma unroll 11
        for (int k = k0; k < k0 + 77; ++k) {
            const float w = A_W[k * HID + c];
            a0 = fmaf(vs[0][k], w, a0);
            a1 = fmaf(vs[1][k], w, a1);
        }
    }
    part[s][0][c] = a0; part[s][1][c] = a1;
    __syncthreads();
    for (int t = threadIdx.x; t < RPB * HID; t += 512) {
        const int r = t / HID, cc = t % HID;
        float acc = A_b[cc];
#pragma unroll
        for (int s2 = 0; s2 < 4; ++s2) acc += part[s2][r][cc];
        uu[(i0 + r) * HID + cc] = tanhf(acc);
    }
}

// ---------------------------------------------------------------------------
// K2 (fused): identical to rounds 7-11 (known-good).
// ---------------------------------------------------------------------------
__global__ __launch_bounds__(640) void k_fused(
    const float* __restrict__ uu, const int* __restrict__ indices,
    const int* __restrict__ nf,
    fp B_W, fp B_b, fp B2_Wo, fp B2_bo,
    fp W1r, fp b1r, fp W1c, fp b1c, fp W1e, fp b1e,
    float* __restrict__ hlhr) {
    __shared__ __align__(16) float ww[RPB][5 * HID];
    __shared__ float part[5][RPB][128];
    __shared__ __align__(16) float bbs[RPB][HID];
    __shared__ __align__(16) float oos[RPB][HID];
    __shared__ int flags[6];
    __shared__ int smode[2];

    if (threadIdx.x < 6) flags[threadIdx.x] = 0;
    __syncthreads();
    if (threadIdx.x < 192) {
        const int t = threadIdx.x;
        const unsigned vn = (unsigned)nf[t];
        if (vn > 1u) atomicOr(&flags[0], 1);
        if (vn & 0xFEFEFEFEu) atomicOr(&flags[1], 1);
        if ((t & 1) && vn) atomicOr(&flags[2], 1);
        if (!(t & 1) && vn) atomicOr(&flags[3], 1);
        const unsigned vi = (unsigned)indices[t];
        if ((t & 1) && vi) atomicOr(&flags[4], 1);
        if (!(t & 1) && vi) atomicOr(&flags[5], 1);
    }
    __syncthreads();
    if (threadIdx.x == 0) {
        int m = 0;
        if (!flags[1] && flags[0]) m = 1;
        else if (!flags[2] && flags[3]) m = 2;
        smode[0] = m;
        smode[1] = (!flags[4] && flags[5]) ? 1 : 0;
    }
    __syncthreads();
    const int mnf = smode[0], midx = smode[1];

    const int i0 = blockIdx.x * RPB;
    for (int t = threadIdx.x; t < RPB * 5 * HID; t += 640) {
        const int r = t / (5 * HID), u = t % (5 * HID);
        const int i = i0 + r;
        const bool notf = (mnf == 1) ? (((const unsigned char*)nf)[i] != 0)
                        : (mnf == 2) ? (nf[2 * i] != 0)
                                     : (nf[i] != 0);
        const int q = u / HID, cc = u % HID;
        int j = midx ? indices[2 * (i * 5 + q)] : indices[i * 5 + q];
        j = (j < 0) ? 0 : ((j >= NW) ? NW - 1 : j);
        ww[r][u] = notf ? 0.f : uu[j * HID + cc];
    }
    __syncthreads();

    const int c = threadIdx.x % 128;
    const int s = threadIdx.x / 128;

    {
        float a0 = 0.f, a1 = 0.f;
        if (c < HID) {
            const int k0 = s * 100;
#pragma unroll 5
            for (int k = k0; k < k0 + 100; k += 4) {
                const float4 w0 = *(const float4*)&ww[0][k];
                const float4 w1 = *(const float4*)&ww[1][k];
                const float b0 = B_W[(k + 0) * HID + c];
                const float b1v = B_W[(k + 1) * HID + c];
                const float b2v = B_W[(k + 2) * HID + c];
                const float b3 = B_W[(k + 3) * HID + c];
                a0 = fmaf(w0.x, b0, a0); a1 = fmaf(w1.x, b0, a1);
                a0 = fmaf(w0.y, b1v, a0); a1 = fmaf(w1.y, b1v, a1);
                a0 = fmaf(w0.z, b2v, a0); a1 = fmaf(w1.z, b2v, a1);
                a0 = fmaf(w0.w, b3, a0); a1 = fmaf(w1.w, b3, a1);
            }
        }
        part[s][0][c] = a0; part[s][1][c] = a1;
    }
    __syncthreads();
    for (int t = threadIdx.x; t < RPB * HID; t += 640) {
        const int r = t / HID, cc = t % HID;
        float acc = B_b[cc];
#pragma unroll
        for (int s2 = 0; s2 < 5; ++s2) acc += part[s2][r][cc];
        bbs[r][cc] = tanhf(acc);
    }
    __syncthreads();

    {
        float a0 = 0.f, a1 = 0.f;
        if (c < HID) {
            const int k0 = s * 20;
#pragma unroll 5
            for (int k = k0; k < k0 + 20; k += 4) {
                const float4 w0 = *(const float4*)&bbs[0][k];
                const float4 w1 = *(const float4*)&bbs[1][k];
                const float b0 = B2_Wo[(k + 0) * HID + c];
                const float b1v = B2_Wo[(k + 1) * HID + c];
                const float b2v = B2_Wo[(k + 2) * HID + c];
                const float b3 = B2_Wo[(k + 3) * HID + c];
                a0 = fmaf(w0.x, b0, a0); a1 = fmaf(w1.x, b0, a1);
                a0 = fmaf(w0.y, b1v, a0); a1 = fmaf(w1.y, b1v, a1);
                a0 = fmaf(w0.z, b2v, a0); a1 = fmaf(w1.z, b2v, a1);
                a0 = fmaf(w0.w, b3, a0); a1 = fmaf(w1.w, b3, a1);
            }
        }
        part[s][0][c] = a0; part[s][1][c] = a1;
    }
    __syncthreads();
    for (int t = threadIdx.x; t < RPB * HID; t += 640) {
        const int r = t / HID, cc = t % HID;
        float acc = B2_bo[cc];
#pragma unroll
        for (int s2 = 0; s2 < 5; ++s2) acc += part[s2][r][cc];
        oos[r][cc] = tanhf(acc);
    }
    __syncthreads();

    const int u = threadIdx.x;
    if (u < 600) {
        const int ho = u / HID;
        const int cc = u % HID;
        const int h = ho >> 1, half = ho & 1;
        fp W1 = (h == 0) ? W1r : ((h == 1) ? W1c : W1e);
        fp b1 = (h == 0) ? b1r : ((h == 1) ? b1c : b1e);
        const float bias = half ? 0.f : b1[cc];
        float a0 = bias, a1 = bias;
        const float* Wp = W1 + half * HID * HID;
#pragma unroll 5
        for (int k = 0; k < HID; k += 4) {
            const float4 o0 = *(const float4*)&oos[0][k];
            const float4 o1 = *(const float4*)&oos[1][k];
            const float b0 = Wp[(k + 0) * HID + cc];
            const float b1v = Wp[(k + 1) * HID + cc];
            const float b2v = Wp[(k + 2) * HID + cc];
            const float b3 = Wp[(k + 3) * HID + cc];
            a0 = fmaf(o0.x, b0, a0); a1 = fmaf(o1.x, b0, a1);
            a0 = fmaf(o0.y, b1v, a0); a1 = fmaf(o1.y, b1v, a1);
            a0 = fmaf(o0.z, b2v, a0); a1 = fmaf(o1.z, b2v, a1);
            a0 = fmaf(o0.w, b3, a0); a1 = fmaf(o1.w, b3, a1);
        }
        hlhr[(size_t)ho * (NW * HID) + (size_t)(i0 + 0) * HID + cc] = a0;
        hlhr[(size_t)ho * (NW * HID) + (size_t)(i0 + 1) * HID + cc] = a1;
    }
}

// ---------------------------------------------------------------------------
// K3 v7 (packed-FP32): out[h][i][j][:] = relu(hl_i + hr_j) @ W2h + b2h
// 32x32 tile / block (256 thr), 2i x 2j(one f32x2 pair) micro-tile.
// j-pair packing: pk_add + pk_max + 2x pk_fma cover 2 j's x 2 channels
// -> ~2.25 VALU ops per (i,j,k) vs 4 scalar. hr staged k-major as f32x2
// pairs (pad-transpose); W2 pre-duplicated {wa,wa,wb,wb} so the inner
// loop reads 1 b128 broadcast + 1 b64 per k. LDS 28.2 KB -> 5 blocks/CU.
// ---------------------------------------------------------------------------
__global__ __launch_bounds__(256, 4) void k_pair(
    const float* __restrict__ hlhr,
    fp W2r, fp b2r, fp W2c, fp b2c, fp W2e, fp b2e,
    float* __restrict__ out) {
    __shared__ __align__(16) float hlS[TP * LDP];      // 13.8 KB (pad + hl)
    __shared__ __align__(16) f32x2 hrK[HID][TP / 2];   // 12.8 KB k-major pairs
    __shared__ __align__(16) f32x4 w2q[HID];           // {wa,wa,wb,wb}

    const int h  = blockIdx.z;
    const int i0 = blockIdx.y * TP;
    const int j0 = blockIdx.x * TP;
    const float* hl = hlhr + (size_t)(h * 2 + 0) * (NW * HID) + (size_t)i0 * HID;
    const float* hr = hlhr + (size_t)(h * 2 + 1) * (NW * HID) + (size_t)j0 * HID;
    fp W2 = (h == 0) ? W2r : ((h == 1) ? W2c : W2e);
    fp b2 = (h == 0) ? b2r : ((h == 1) ? b2c : b2e);
    const int tid = threadIdx.x;

    // 1) hr rows -> pad (row-major, coalesced); build w2q
    for (int t = tid; t < TP * HID; t += 256) {
        const int r = t / HID, c = t % HID;
        hlS[r * LDP + c] = hr[t];
    }
    if (tid < HID) {
        const float wa = W2[2 * tid], wb = W2[2 * tid + 1];
        w2q[tid] = (f32x4){wa, wa, wb, wb};
    }
    __syncthreads();
    // 2) transpose pad -> hrK (k-major; writes stride-1, conflict-free)
    {
        float* hrKf = (float*)hrK;
        for (int t = tid; t < HID * TP; t += 256) {
            const int k = t >> 5, j = t & 31;
            hrKf[k * TP + j] = hlS[j * LDP + k];
        }
    }
    __syncthreads();
    // 3) hl rows -> hlS (overwrite pad)
    for (int t = tid; t < TP * HID; t += 256) {
        const int r = t / HID, c = t % HID;
        hlS[r * LDP + c] = hl[t];
    }
    __syncthreads();

    const int tx = tid & 15;   // j-pair: j = 2tx, 2tx+1
    const int ty = tid >> 4;   // i rows 2ty, 2ty+1
    f32x2 aA0 = {0.f, 0.f}, aB0 = {0.f, 0.f};
    f32x2 aA1 = {0.f, 0.f}, aB1 = {0.f, 0.f};
    const f32x2 zero2 = {0.f, 0.f};

    for (int kb = 0; kb < HID; kb += 4) {
        const float4 h0 = *(const float4*)&hlS[(2 * ty + 0) * LDP + kb];
        const float4 h1 = *(const float4*)&hlS[(2 * ty + 1) * LDP + kb];
#define STEP(q, cmp)                                                           \
        {                                                                      \
            const f32x4 wq = w2q[kb + q];                                      \
            const f32x2 wa = {wq.x, wq.y};                                     \
            const f32x2 wb = {wq.z, wq.w};                                     \
            const f32x2 rp = hrK[kb + q][tx];                                  \
            const f32x2 a0d = {h0.cmp, h0.cmp};                                \
            const f32x2 a1d = {h1.cmp, h1.cmp};                                \
            const f32x2 t0 = __builtin_elementwise_max(a0d + rp, zero2);       \
            const f32x2 t1 = __builtin_elementwise_max(a1d + rp, zero2);       \
            aA0 = __builtin_elementwise_fma(t0, wa, aA0);                      \
            aB0 = __builtin_elementwise_fma(t0, wb, aB0);                      \
            aA1 = __builtin_elementwise_fma(t1, wa, aA1);                      \
            aB1 = __builtin_elementwise_fma(t1, wb, aB1);                      \
        }
        STEP(0, x) STEP(1, y) STEP(2, z) STEP(3, w)
#undef STEP
    }

    const float b20 = b2[0];
    const float b21 = b2[1];
    {
        const int i = i0 + 2 * ty;
        const int j = j0 + 2 * tx;
        const size_t o0 = ((size_t)(h * NW + i + 0) * NW + j) * 2;
        const size_t o1 = ((size_t)(h * NW + i + 1) * NW + j) * 2;
        float4 v0, v1;
        v0.x = aA0.x + b20; v0.y = aB0.x + b21;
        v0.z = aA0.y + b20; v0.w = aB0.y + b21;
        v1.x = aA1.x + b20; v1.y = aB1.x + b21;
        v1.z = aA1.y + b20; v1.w = aB1.y + b21;
        *reinterpret_cast<float4*>(out + o0) = v0;
        *reinterpret_cast<float4*>(out + o1) = v1;
    }
}

// ---------------------------------------------------------------------------
extern "C" void kernel_launch(void* const* d_in, const int* in_sizes, int n_in,
                              void* d_out, int out_size, void* d_ws,
                              size_t ws_size, hipStream_t stream) {
    int i_vv = -1, i_idx = -1, i_nf = -1, i_AW = -1, i_BW = -1;
    int tens[3] = {-1, -1, -1}; int n10 = 0;   // B2_Wo, B2_Wh, D_W
    int w1s[3]  = {-1, -1, -1}; int n20 = 0;
    int w2s_[3] = {-1, -1, -1}; int n200 = 0;
    int b100[8] = {-1, -1, -1, -1, -1, -1, -1, -1}; int nb = 0;
    int b2s[3]  = {-1, -1, -1}; int nb2 = 0;
    for (int i = 0; i < n_in; ++i) {
        switch (in_sizes[i]) {
            case 236544: i_vv = i; break;
            case 3840:   i_idx = i; break;
            case 768:    i_nf = i; break;
            case 30800:  i_AW = i; break;
            case 60000:  i_BW = i; break;
            case 10000:  if (n10 < 3) tens[n10++] = i; break;
            case 20000:  if (n20 < 3) w1s[n20++] = i; break;
            case 200:    if (n200 < 3) w2s_[n200++] = i; break;
            case 100:    if (nb < 8) b100[nb++] = i; break;
            case 2:      if (nb2 < 3) b2s[nb2++] = i; break;
            default: break;  // num_words (size 1)
        }
    }
    fp vv          = (fp)d_in[i_vv];
    const int* idx = (const int*)d_in[i_idx];
    const int* nf  = (const int*)d_in[i_nf];
    fp A_W = (fp)d_in[i_AW],      A_b   = (fp)d_in[b100[0]];
    fp B_W = (fp)d_in[i_BW],      B_b   = (fp)d_in[b100[1]];
    fp B2_Wo = (fp)d_in[tens[0]], B2_bo = (fp)d_in[b100[2]];
    fp W1r = (fp)d_in[w1s[0]], b1r = (fp)d_in[b100[5]];
    fp W1c = (fp)d_in[w1s[1]], b1c = (fp)d_in[b100[6]];
    fp W1e = (fp)d_in[w1s[2]], b1e = (fp)d_in[b100[7]];
    fp W2r = (fp)d_in[w2s_[0]], b2r = (fp)d_in[b2s[0]];
    fp W2c = (fp)d_in[w2s_[1]], b2c = (fp)d_in[b2s[1]];
    fp W2e = (fp)d_in[w2s_[2]], b2e = (fp)d_in[b2s[2]];

    float* out = (float*)d_out;

    float* ws   = (float*)d_ws;
    float* uu   = ws;                       // 768*100 f32
    float* hlhr = ws + NW * HID;            // [6][768][100] f32

    k_uu<<<NW / RPB, 512, 0, stream>>>(vv, A_W, A_b, uu);
    k_fused<<<NW / RPB, 640, 0, stream>>>(uu, idx, nf, B_W, B_b,
                                          B2_Wo, B2_bo,
                                          W1r, b1r, W1c, b1c, W1e, b1e, hlhr);
    dim3 grid(NW / TP, NW / TP, 3);
    k_pair<<<grid, 256, 0, stream>>>(hlhr, W2r, b2r, W2c, b2c, W2e, b2e, out);
}

// Round 14
// 51.620 us; speedup vs baseline: 2.3396x; 1.0878x over previous
//
#include <hip/hip_runtime.h>
#include <hip/hip_bf16.h>

// Problem constants (reference: N=768, D_IN=308, H=100, iterations=1)
// Inputs f32, output f32 (verified round 4). hh==0 on the single iteration,
// so B_W[500:600], B2_Wh, D_W/b are dead.
#define NW   768
#define HID  100
#define DIN  308
#define RPB  2          // rows per block in k_uu / k_fused
#define TQ   64         // pair-tile edge (v8)
#define LDP  108        // LDS row stride: mod4==0 (aligned b128), mod32==12

typedef const float* fp;

// ---------------------------------------------------------------------------
// K1: uu = tanh(vv @ A_W + A_b).  (identical to rounds 7-13)
// ---------------------------------------------------------------------------
__global__ __launch_bounds__(512) void k_uu(fp vv, fp A_W, fp A_b,
                                            float* __restrict__ uu) {
    __shared__ float vs[RPB][DIN];
    __shared__ float part[4][RPB][128];
    const int i0 = blockIdx.x * RPB;
    for (int t = threadIdx.x; t < RPB * DIN; t += 512) {
        const int r = t / DIN, k = t % DIN;
        vs[r][k] = vv[(i0 + r) * DIN + k];
    }
    __syncthreads();
    const int c = threadIdx.x & 127;
    const int s = threadIdx.x >> 7;
    float a0 = 0.f, a1 = 0.f;
    if (c < HID) {
        const int k0 = s * 77;
#pragma unroll 11
        for (int k = k0; k < k0 + 77; ++k) {
            const float w = A_W[k * HID + c];
            a0 = fmaf(vs[0][k], w, a0);
            a1 = fmaf(vs[1][k], w, a1);
        }
    }
    part[s][0][c] = a0; part[s][1][c] = a1;
    __syncthreads();
    for (int t = threadIdx.x; t < RPB * HID; t += 512) {
        const int r = t / HID, cc = t % HID;
        float acc = A_b[cc];
#pragma unroll
        for (int s2 = 0; s2 < 4; ++s2) acc += part[s2][r][cc];
        uu[(i0 + r) * HID + cc] = tanhf(acc);
    }
}

// ---------------------------------------------------------------------------
// K2 (fused): identical to rounds 7-13 (known-good).
// ---------------------------------------------------------------------------
__global__ __launch_bounds__(640) void k_fused(
    const float* __restrict__ uu, const int* __restrict__ indices,
    const int* __restrict__ nf,
    fp B_W, fp B_b, fp B2_Wo, fp B2_bo,
    fp W1r, fp b1r, fp W1c, fp b1c, fp W1e, fp b1e,
    float* __restrict__ hlhr) {
    __shared__ __align__(16) float ww[RPB][5 * HID];
    __shared__ float part[5][RPB][128];
    __shared__ __align__(16) float bbs[RPB][HID];
    __shared__ __align__(16) float oos[RPB][HID];
    __shared__ int flags[6];
    __shared__ int smode[2];

    if (threadIdx.x < 6) flags[threadIdx.x] = 0;
    __syncthreads();
    if (threadIdx.x < 192) {
        const int t = threadIdx.x;
        const unsigned vn = (unsigned)nf[t];
        if (vn > 1u) atomicOr(&flags[0], 1);
        if (vn & 0xFEFEFEFEu) atomicOr(&flags[1], 1);
        if ((t & 1) && vn) atomicOr(&flags[2], 1);
        if (!(t & 1) && vn) atomicOr(&flags[3], 1);
        const unsigned vi = (unsigned)indices[t];
        if ((t & 1) && vi) atomicOr(&flags[4], 1);
        if (!(t & 1) && vi) atomicOr(&flags[5], 1);
    }
    __syncthreads();
    if (threadIdx.x == 0) {
        int m = 0;
        if (!flags[1] && flags[0]) m = 1;
        else if (!flags[2] && flags[3]) m = 2;
        smode[0] = m;
        smode[1] = (!flags[4] && flags[5]) ? 1 : 0;
    }
    __syncthreads();
    const int mnf = smode[0], midx = smode[1];

    const int i0 = blockIdx.x * RPB;
    for (int t = threadIdx.x; t < RPB * 5 * HID; t += 640) {
        const int r = t / (5 * HID), u = t % (5 * HID);
        const int i = i0 + r;
        const bool notf = (mnf == 1) ? (((const unsigned char*)nf)[i] != 0)
                        : (mnf == 2) ? (nf[2 * i] != 0)
                                     : (nf[i] != 0);
        const int q = u / HID, cc = u % HID;
        int j = midx ? indices[2 * (i * 5 + q)] : indices[i * 5 + q];
        j = (j < 0) ? 0 : ((j >= NW) ? NW - 1 : j);
        ww[r][u] = notf ? 0.f : uu[j * HID + cc];
    }
    __syncthreads();

    const int c = threadIdx.x % 128;
    const int s = threadIdx.x / 128;

    {
        float a0 = 0.f, a1 = 0.f;
        if (c < HID) {
            const int k0 = s * 100;
#pragma unroll 5
            for (int k = k0; k < k0 + 100; k += 4) {
                const float4 w0 = *(const float4*)&ww[0][k];
                const float4 w1 = *(const float4*)&ww[1][k];
                const float b0 = B_W[(k + 0) * HID + c];
                const float b1v = B_W[(k + 1) * HID + c];
                const float b2v = B_W[(k + 2) * HID + c];
                const float b3 = B_W[(k + 3) * HID + c];
                a0 = fmaf(w0.x, b0, a0); a1 = fmaf(w1.x, b0, a1);
                a0 = fmaf(w0.y, b1v, a0); a1 = fmaf(w1.y, b1v, a1);
                a0 = fmaf(w0.z, b2v, a0); a1 = fmaf(w1.z, b2v, a1);
                a0 = fmaf(w0.w, b3, a0); a1 = fmaf(w1.w, b3, a1);
            }
        }
        part[s][0][c] = a0; part[s][1][c] = a1;
    }
    __syncthreads();
    for (int t = threadIdx.x; t < RPB * HID; t += 640) {
        const int r = t / HID, cc = t % HID;
        float acc = B_b[cc];
#pragma unroll
        for (int s2 = 0; s2 < 5; ++s2) acc += part[s2][r][cc];
        bbs[r][cc] = tanhf(acc);
    }
    __syncthreads();

    {
        float a0 = 0.f, a1 = 0.f;
        if (c < HID) {
            const int k0 = s * 20;
#pragma unroll 5
            for (int k = k0; k < k0 + 20; k += 4) {
                const float4 w0 = *(const float4*)&bbs[0][k];
                const float4 w1 = *(const float4*)&bbs[1][k];
                const float b0 = B2_Wo[(k + 0) * HID + c];
                const float b1v = B2_Wo[(k + 1) * HID + c];
                const float b2v = B2_Wo[(k + 2) * HID + c];
                const float b3 = B2_Wo[(k + 3) * HID + c];
                a0 = fmaf(w0.x, b0, a0); a1 = fmaf(w1.x, b0, a1);
                a0 = fmaf(w0.y, b1v, a0); a1 = fmaf(w1.y, b1v, a1);
                a0 = fmaf(w0.z, b2v, a0); a1 = fmaf(w1.z, b2v, a1);
                a0 = fmaf(w0.w, b3, a0); a1 = fmaf(w1.w, b3, a1);
            }
        }
        part[s][0][c] = a0; part[s][1][c] = a1;
    }
    __syncthreads();
    for (int t = threadIdx.x; t < RPB * HID; t += 640) {
        const int r = t / HID, cc = t % HID;
        float acc = B2_bo[cc];
#pragma unroll
        for (int s2 = 0; s2 < 5; ++s2) acc += part[s2][r][cc];
        oos[r][cc] = tanhf(acc);
    }
    __syncthreads();

    const int u = threadIdx.x;
    if (u < 600) {
        const int ho = u / HID;
        const int cc = u % HID;
        const int h = ho >> 1, half = ho & 1;
        fp W1 = (h == 0) ? W1r : ((h == 1) ? W1c : W1e);
        fp b1 = (h == 0) ? b1r : ((h == 1) ? b1c : b1e);
        const float bias = half ? 0.f : b1[cc];
        float a0 = bias, a1 = bias;
        const float* Wp = W1 + half * HID * HID;
#pragma unroll 5
        for (int k = 0; k < HID; k += 4) {
            const float4 o0 = *(const float4*)&oos[0][k];
            const float4 o1 = *(const float4*)&oos[1][k];
            const float b0 = Wp[(k + 0) * HID + cc];
            const float b1v = Wp[(k + 1) * HID + cc];
            const float b2v = Wp[(k + 2) * HID + cc];
            const float b3 = Wp[(k + 3) * HID + cc];
            a0 = fmaf(o0.x, b0, a0); a1 = fmaf(o1.x, b0, a1);
            a0 = fmaf(o0.y, b1v, a0); a1 = fmaf(o1.y, b1v, a1);
            a0 = fmaf(o0.z, b2v, a0); a1 = fmaf(o1.z, b2v, a1);
            a0 = fmaf(o0.w, b3, a0); a1 = fmaf(o1.w, b3, a1);
        }
        hlhr[(size_t)ho * (NW * HID) + (size_t)(i0 + 0) * HID + cc] = a0;
        hlhr[(size_t)ho * (NW * HID) + (size_t)(i0 + 1) * HID + cc] = a1;
    }
}

// ---------------------------------------------------------------------------
// K3 v8 (arithmetic-intensity): out[h][i][j][:] = relu(hl_i+hr_j)@W2h + b2h
// 64x64 tile / block (256 thr), 4i x 4j micro-tile (strided j-groups).
// LDS reads per 4k per thread: 4 hl + 4 hr b128 for 256 lane-ops
// (0.031 b128/op, 3x better than v6) -> VALU-bound, not LDS-bound.
// W2 via wave-uniform global float4 reads -> s_load (zero LDS/VALU).
// Bank math (LDP=108): hl rows {4ty+ii}: 2-way (free); hr rows tx+16g at
// stride 12 mod 32: 8 distinct 4-bank starts x2 -> 2-way (free).
// LDS 55.3 KB -> 2 blocks/CU.
// ---------------------------------------------------------------------------
__global__ __launch_bounds__(256, 2) void k_pair(
    const float* __restrict__ hlhr,
    fp W2r, fp b2r, fp W2c, fp b2c, fp W2e, fp b2e,
    float* __restrict__ out) {
    __shared__ __align__(16) float hlS[TQ * LDP];
    __shared__ __align__(16) float hrS[TQ * LDP];

    const int h  = blockIdx.z;
    const int i0 = blockIdx.y * TQ;
    const int j0 = blockIdx.x * TQ;
    const float* hl = hlhr + (size_t)(h * 2 + 0) * (NW * HID) + (size_t)i0 * HID;
    const float* hr = hlhr + (size_t)(h * 2 + 1) * (NW * HID) + (size_t)j0 * HID;
    fp W2 = (h == 0) ? W2r : ((h == 1) ? W2c : W2e);
    fp b2 = (h == 0) ? b2r : ((h == 1) ? b2c : b2e);
    const int tid = threadIdx.x;

    for (int t = tid; t < TQ * HID; t += 256) {
        const int r = t / HID, c = t % HID;
        hlS[r * LDP + c] = hl[t];                // coalesced global reads
        hrS[r * LDP + c] = hr[t];
    }
    __syncthreads();

    const int tx = tid & 15;    // j-groups: tx, tx+16, tx+32, tx+48
    const int ty = tid >> 4;    // i rows 4ty .. 4ty+3
    float acc0[4][4] = {};      // [ii][g] channel 0
    float acc1[4][4] = {};      // [ii][g] channel 1

    for (int kb = 0; kb < HID; kb += 4) {
        // W2[k][c] = W2[2k+c]; two uniform 16B loads cover k=kb..kb+3
        const float4 wA = *(const float4*)&W2[2 * kb];      // wa0,wb0,wa1,wb1
        const float4 wB = *(const float4*)&W2[2 * kb + 4];  // wa2,wb2,wa3,wb3
        const float4 a0 = *(const float4*)&hlS[(4 * ty + 0) * LDP + kb];
        const float4 a1 = *(const float4*)&hlS[(4 * ty + 1) * LDP + kb];
        const float4 a2 = *(const float4*)&hlS[(4 * ty + 2) * LDP + kb];
        const float4 a3 = *(const float4*)&hlS[(4 * ty + 3) * LDP + kb];
        const float4 r0 = *(const float4*)&hrS[(tx +  0) * LDP + kb];
        const float4 r1 = *(const float4*)&hrS[(tx + 16) * LDP + kb];
        const float4 r2 = *(const float4*)&hrS[(tx + 32) * LDP + kb];
        const float4 r3 = *(const float4*)&hrS[(tx + 48) * LDP + kb];
#define STEP(cmp, wa, wb)                                                      \
        {                                                                      \
            const float av[4] = {a0.cmp, a1.cmp, a2.cmp, a3.cmp};              \
            const float rv[4] = {r0.cmp, r1.cmp, r2.cmp, r3.cmp};              \
            _Pragma("unroll")                                                  \
            for (int ii = 0; ii < 4; ++ii) {                                   \
                _Pragma("unroll")                                              \
                for (int g = 0; g < 4; ++g) {                                  \
                    const float hv = fmaxf(av[ii] + rv[g], 0.f);               \
                    acc0[ii][g] = fmaf(hv, wa, acc0[ii][g]);                   \
                    acc1[ii][g] = fmaf(hv, wb, acc1[ii][g]);                   \
                }                                                              \
            }                                                                  \
        }
        STEP(x, wA.x, wA.y) STEP(y, wA.z, wA.w)
        STEP(z, wB.x, wB.y) STEP(w, wB.z, wB.w)
#undef STEP
    }

    const float b20 = b2[0];
    const float b21 = b2[1];
#pragma unroll
    for (int ii = 0; ii < 4; ++ii) {
        const int i = i0 + 4 * ty + ii;
#pragma unroll
        for (int g = 0; g < 4; ++g) {
            const int j = j0 + tx + 16 * g;
            const size_t o = ((size_t)(h * NW + i) * NW + j) * 2;
            float2 v;
            v.x = acc0[ii][g] + b20;
            v.y = acc1[ii][g] + b21;
            *reinterpret_cast<float2*>(out + o) = v;
        }
    }
}

// ---------------------------------------------------------------------------
extern "C" void kernel_launch(void* const* d_in, const int* in_sizes, int n_in,
                              void* d_out, int out_size, void* d_ws,
                              size_t ws_size, hipStream_t stream) {
    int i_vv = -1, i_idx = -1, i_nf = -1, i_AW = -1, i_BW = -1;
    int tens[3] = {-1, -1, -1}; int n10 = 0;   // B2_Wo, B2_Wh, D_W
    int w1s[3]  = {-1, -1, -1}; int n20 = 0;
    int w2s_[3] = {-1, -1, -1}; int n200 = 0;
    int b100[8] = {-1, -1, -1, -1, -1, -1, -1, -1}; int nb = 0;
    int b2s[3]  = {-1, -1, -1}; int nb2 = 0;
    for (int i = 0; i < n_in; ++i) {
        switch (in_sizes[i]) {
            case 236544: i_vv = i; break;
            case 3840:   i_idx = i; break;
            case 768:    i_nf = i; break;
            case 30800:  i_AW = i; break;
            case 60000:  i_BW = i; break;
            case 10000:  if (n10 < 3) tens[n10++] = i; break;
            case 20000:  if (n20 < 3) w1s[n20++] = i; break;
            case 200:    if (n200 < 3) w2s_[n200++] = i; break;
            case 100:    if (nb < 8) b100[nb++] = i; break;
            case 2:      if (nb2 < 3) b2s[nb2++] = i; break;
            default: break;  // num_words (size 1)
        }
    }
    fp vv          = (fp)d_in[i_vv];
    const int* idx = (const int*)d_in[i_idx];
    const int* nf  = (const int*)d_in[i_nf];
    fp A_W = (fp)d_in[i_AW],      A_b   = (fp)d_in[b100[0]];
    fp B_W = (fp)d_in[i_BW],      B_b   = (fp)d_in[b100[1]];
    fp B2_Wo = (fp)d_in[tens[0]], B2_bo = (fp)d_in[b100[2]];
    fp W1r = (fp)d_in[w1s[0]], b1r = (fp)d_in[b100[5]];
    fp W1c = (fp)d_in[w1s[1]], b1c = (fp)d_in[b100[6]];
    fp W1e = (fp)d_in[w1s[2]], b1e = (fp)d_in[b100[7]];
    fp W2r = (fp)d_in[w2s_[0]], b2r = (fp)d_in[b2s[0]];
    fp W2c = (fp)d_in[w2s_[1]], b2c = (fp)d_in[b2s[1]];
    fp W2e = (fp)d_in[w2s_[2]], b2e = (fp)d_in[b2s[2]];

    float* out = (float*)d_out;

    float* ws   = (float*)d_ws;
    float* uu   = ws;                       // 768*100 f32
    float* hlhr = ws + NW * HID;            // [6][768][100] f32

    k_uu<<<NW / RPB, 512, 0, stream>>>(vv, A_W, A_b, uu);
    k_fused<<<NW / RPB, 640, 0, stream>>>(uu, idx, nf, B_W, B_b,
                                          B2_Wo, B2_bo,
                                          W1r, b1r, W1c, b1c, W1e, b1e, hlhr);
    dim3 grid(NW / TQ, NW / TQ, 3);
    k_pair<<<grid, 256, 0, stream>>>(hlhr, W2r, b2r, W2c, b2c, W2e, b2e, out);
}